// Round 12
// baseline (119.139 us; speedup 1.0000x reference)
//
#include <hip/hip_runtime.h>

#define N_ELEM 4096
#define BLOCK 128          // R21: TWO waves per row -> 4 waves/SIMD
#define PER 32             // elems per thread
#define NG (PER / 2)       // 16 v2f groups
#define NWAVE 2
#define CAPACITY 600.0f
#define DAMPING 1e-3f
// R19/R20 post-mortem: inline-asm v_pk_fma_f32/v_pk_mul_f32 path produced
// NaN on HW (compiled+ran, output NaN) — unexplained asm/operand hazard;
// SHELVED per rigor rules (no blind retries). Reverted to R18's plain-C++
// v2f math, which is issue-model-calibrated (80 cy/group == measured).
// R21: ONE structural change vs R18 — split each row across 2 waves
// (BLOCK 64->128, PER 64->32). Grid 2048 blocks x 2 waves = 4096 waves =
// 4 waves/SIMD (R18 was grid-capped at 2) -> 2x latency hiding for the
// ELEM_CORE dependency chain (fma->sqrt->add->mul->rcp->..., 2 trans ops).
// Per-wave data halves (64 floats) -> fits 128 VGPR cap of
// launch_bounds(128,4); no AGPR parking pressure. Cost: one tiny
// cross-wave combine/iter (2x lane63 v2f LDS write + barrier + 8B read),
// ~40 insts vs ~15K compute insts/iter. Element math, mu schedule, gate,
// emit refine: byte-identical to R18; only sum grouping changes (ulps).
// Schedule (R16-proven): 3 warmup (mu=1) + 4 ladder (x1/4) + final-mu
// Newtons; gate |dl|<1e-5 at it>=9 (fires ~it 9-11); cap 13; break
// WITHOUT applying dlam; emit = KKT refine at (lam, dlam).
#define NITER 13
#define N_MU1 3
#define FIRST_FINAL 7      // first it with mu = DAMPING
#define GATE_IT 9
#define GATE_EPS 1e-5f

typedef float v2f __attribute__((ext_vector_type(2)));
union F4V2 { float4 f4; v2f v[2]; };

__device__ __forceinline__ float raw_rcp(float a)  { return __builtin_amdgcn_rcpf(a); }
__device__ __forceinline__ float raw_sqrt(float a) { return __builtin_amdgcn_sqrtf(a); }
__device__ __forceinline__ v2f pk_rcp(v2f a) {
    v2f r; r.x = raw_rcp(a.x); r.y = raw_rcp(a.y); return r;
}
__device__ __forceinline__ v2f pk_sqrt(v2f a) {
    v2f r; r.x = raw_sqrt(a.x); r.y = raw_sqrt(a.y); return r;
}
__device__ __forceinline__ v2f pk_copysign(v2f m, v2f s) {
    v2f r; r.x = __builtin_copysignf(m.x, s.x); r.y = __builtin_copysignf(m.y, s.y);
    return r;
}

// DPP-based wave64 sum (HW-verified R17/R18). All-VALU, no LDS. After the
// 6 steps lane 63 holds the wave total.
template <int CTRL, int RMASK>
__device__ __forceinline__ float dpp_add(float v) {
    const int m = __builtin_amdgcn_update_dpp(
        0, __float_as_int(v), CTRL, RMASK, 0xF, false);
    return v + __int_as_float(m);
}
__device__ __forceinline__ float wave_sum63(float v) {
    v = dpp_add<0x111, 0xF>(v);   // row_shr:1
    v = dpp_add<0x112, 0xF>(v);   // row_shr:2
    v = dpp_add<0x114, 0xF>(v);   // row_shr:4
    v = dpp_add<0x118, 0xF>(v);   // row_shr:8
    v = dpp_add<0x142, 0xA>(v);   // row_bcast:15
    v = dpp_add<0x143, 0xC>(v);   // row_bcast:31 -> lane63 = wave total
    return v;
}

// Per-element core (UNCHANGED from R15..R18 — verified). Quadratic
// r x^2 - (r+2mu) x + mu = 0; D = r^2+4mu^2 exact; den = |r|+2mu+sqrt(D)
// (no cancellation); x' = 2mu/den; x = 0.5 - copysign(0.5-x', r);
// AB2 = H*mu = D + 2mu*s (verified identity); rq = rcp(den*AB2) serves
// both 1/den (rq*AB2, AB2 cancels exactly in x') and 1/AB2 (rq*den).
#define ELEM_CORE(r_, wk_, wsq_, s0_, s2_)                                 \
    {                                                                      \
        const v2f a_   = __builtin_elementwise_abs(r_);                    \
        const v2f D_   = r_ * r_ + mu4sq;                                  \
        const v2f s_   = pk_sqrt(D_);                                      \
        const v2f den_ = (a_ + two_mu) + s_;                               \
        const v2f AB2_ = two_mu * s_ + D_;                                 \
        const v2f rq_  = pk_rcp(den_ * AB2_);                              \
        const v2f xp_  = two_mu * (rq_ * AB2_);                            \
        const v2f xk_  = 0.5f - pk_copysign(0.5f - xp_, r_);               \
        s0_ = wk_ * xk_ + s0_;                                             \
        s2_ = wsq_ * (rq_ * den_) + s2_;                                   \
    }

// Layout: c (32) + w (32) floats in regs + temps (~104 total < 128 cap via
// launch_bounds(128,4) -> 4 waves/SIMD, no spill). No per-element state
// across iterations; emit recomputes x, 1/AB2 once at (lam, dlam).
__global__ __launch_bounds__(BLOCK, 4) void ipm_knapsack_kernel(
        const float* __restrict__ costs,
        const float* __restrict__ weights,
        float* __restrict__ out) {
    __shared__ v2f ldsR[2][NWAVE];        // parity-buffered {s0,s2} per wave
    const int row = blockIdx.x;
    const int t   = threadIdx.x;

    v2f w[NG], c[NG];

    // ---- Load w and this row's c (negated) into registers ----
    const float4* wg = reinterpret_cast<const float4*>(weights);
    const float4* cg = reinterpret_cast<const float4*>(costs + (size_t)row * N_ELEM);
    #pragma unroll
    for (int j = 0; j < NG / 2; ++j) {
        F4V2 ww, cc;
        ww.f4 = wg[t + BLOCK * j];
        cc.f4 = cg[t + BLOCK * j];
        cc.f4.x = -cc.f4.x; cc.f4.y = -cc.f4.y; cc.f4.z = -cc.f4.z; cc.f4.w = -cc.f4.w;
        w[2 * j] = ww.v[0]; w[2 * j + 1] = ww.v[1];
        c[2 * j] = cc.v[0]; c[2 * j + 1] = cc.v[1];
    }

    float lam = 0.0f, dl = 0.0f;

    for (int it = 0; it < NITER; ++it) {
        // mu: 1,1,1, .25, .0625, .015625, .00390625, then DAMPING forever.
        const float mu = (it < N_MU1) ? 1.0f
                       : (it < FIRST_FINAL)
                         ? __uint_as_float((unsigned)(127 - 2 * (it - (N_MU1 - 1))) << 23)
                         : DAMPING;
        const float two_mu = 2.0f * mu;
        const float mu4sq  = 4.0f * mu * mu;

        v2f s0 = {0.0f, 0.0f}, s2 = {0.0f, 0.0f};
        #pragma unroll
        for (int k = 0; k < NG; ++k) {
            const v2f wk  = w[k];
            const v2f wsq = wk * wk;
            const v2f r_  = lam * wk + c[k];
            ELEM_CORE(r_, wk, wsq, s0, s2);
        }

        // ---- Reduce: DPP wave sums; lane63 writes {s0,s2}; barrier;
        // both waves read both entries -> uniform totals on all threads.
        const float s0w = wave_sum63(s0.x + s0.y);
        const float s2w = wave_sum63(s2.x + s2.y);
        const int par  = it & 1;
        const int wv   = t >> 6;
        if ((t & 63) == 63) { v2f p = {s0w, s2w}; ldsR[par][wv] = p; }
        __syncthreads();
        const v2f pa = ldsR[par][0], pb = ldsR[par][1];
        const float s0t = pa.x + pb.x;
        const float s2t = pa.y + pb.y;
        // Schur: dl = (sum(w*x) - cap) / (mu * sum(w^2/AB2))
        dl = (s0t - CAPACITY) * raw_rcp(mu * s2t);

        // Break WITHOUT applying dlam: (lam, dlam) feeds the emit refine.
        // Gate fires ~it 9-11 (R16-proven). dl uniform -> uniform branch.
        if ((it >= GATE_IT && fabsf(dl) < GATE_EPS) || it == NITER - 1) break;
        lam += dl;
    }

    // ---- Emit pass: recompute x, 1/AB2 at (lam, mu=DAMPING); refine:
    // out = x - dlam * (mu*w)/AB2  (== reference _kkt_refine with F1 == 0).
    {
        const float mu = DAMPING;
        const float two_mu = 2.0f * mu;
        const float mu4sq  = 4.0f * mu * mu;
        float4* og = reinterpret_cast<float4*>(out + (size_t)row * N_ELEM);
        #pragma unroll
        for (int j = 0; j < NG / 2; ++j) {
            F4V2 ov;
            #pragma unroll
            for (int h = 0; h < 2; ++h) {
                const int k = 2 * j + h;
                const v2f wk   = w[k];
                const v2f r_   = lam * wk + c[k];
                const v2f a_   = __builtin_elementwise_abs(r_);
                const v2f D_   = r_ * r_ + mu4sq;
                const v2f s_   = pk_sqrt(D_);
                const v2f den_ = (a_ + two_mu) + s_;
                const v2f AB2_ = two_mu * s_ + D_;
                const v2f rq_  = pk_rcp(den_ * AB2_);
                const v2f xp_  = two_mu * (rq_ * AB2_);
                const v2f xk_  = 0.5f - pk_copysign(0.5f - xp_, r_);
                const v2f wi_  = (mu * wk) * (rq_ * den_);
                ov.v[h] = xk_ - dl * wi_;
            }
            og[t + BLOCK * j] = ov.f4;
        }
    }
}

extern "C" void kernel_launch(void* const* d_in, const int* in_sizes, int n_in,
                              void* d_out, int out_size, void* d_ws, size_t ws_size,
                              hipStream_t stream) {
    const float* costs   = (const float*)d_in[0];
    const float* weights = (const float*)d_in[1];
    float* out = (float*)d_out;
    const int B = in_sizes[0] / N_ELEM;   // 2048 rows -> 2048 two-wave blocks
    ipm_knapsack_kernel<<<B, BLOCK, 0, stream>>>(costs, weights, out);
}

// Round 15
// 113.338 us; speedup vs baseline: 1.0512x; 1.0512x over previous
//
#include <hip/hip_runtime.h>

#define N_ELEM 4096
#define BLOCK 64           // ONE WAVE per block -> no barrier, no LDS
#define PER 64             // elems per thread (one row per wave)
#define NG (PER / 2)       // 32 v2f groups
#define CAPACITY 600.0f
#define DAMPING 1e-3f
// R23 post-mortem: NaN with {sign-folding + 16x-step schedule} bundled.
// Mechanism indicts the SCHEDULE: saturated-region lam-Newton diverges
// (residual flat, Schur denom ~ 1/lam^2 -> dl ~ lam^2, lam squares each
// iter -> inf -> rq=rcp(inf)=0 -> xp=0*inf=NaN). R23 jumped mu 1->0.0625
// (16x) after only 2 warmups; every passing variant (R13/15/16/18/21) used
// 3 warmups + 4x steps. Sign-folding is pure algebraic regrouping of
// finite terms — cannot NaN unless lam already diverged.
// R24 bisect: PROVEN schedule (3 warmup, x1/4 ladder, final mu, gate
// 1e-5@it>=9, cap 13) + sign-folding only (+2 inst/elem saved), plus a
// divergence clamp |dl|<=8: provably inert on the proven path (warmup
// steps O(3), gated steps <1e-5) but caps the squaring cascade, making
// future schedule experiments NaN-proof. Path-independence (unique final-
// mu minimizer + certified exit gate) => clamp affects path only, never
// the converged answer.
#define NITER 13
#define N_MU1 3
#define FIRST_FINAL 7      // first it with mu = DAMPING
#define GATE_IT 9
#define GATE_EPS 1e-5f
#define DL_CLAMP 8.0f

typedef float v2f __attribute__((ext_vector_type(2)));
union F4V2 { float4 f4; v2f v[2]; };

__device__ __forceinline__ float raw_rcp(float a)  { return __builtin_amdgcn_rcpf(a); }
__device__ __forceinline__ float raw_sqrt(float a) { return __builtin_amdgcn_sqrtf(a); }
__device__ __forceinline__ v2f pk_rcp(v2f a) {
    v2f r; r.x = raw_rcp(a.x); r.y = raw_rcp(a.y); return r;
}
__device__ __forceinline__ v2f pk_sqrt(v2f a) {
    v2f r; r.x = raw_sqrt(a.x); r.y = raw_sqrt(a.y); return r;
}
__device__ __forceinline__ v2f pk_copysign(v2f m, v2f s) {
    v2f r; r.x = __builtin_copysignf(m.x, s.x); r.y = __builtin_copysignf(m.y, s.y);
    return r;
}

// DPP-based wave64 sum (HW-verified R17/R18/R21). All-VALU, no LDS. After
// the 6 steps lane 63 holds the wave total.
template <int CTRL, int RMASK>
__device__ __forceinline__ float dpp_add(float v) {
    const int m = __builtin_amdgcn_update_dpp(
        0, __float_as_int(v), CTRL, RMASK, 0xF, false);
    return v + __int_as_float(m);
}
__device__ __forceinline__ float wave_sum63(float v) {
    v = dpp_add<0x111, 0xF>(v);   // row_shr:1
    v = dpp_add<0x112, 0xF>(v);   // row_shr:2
    v = dpp_add<0x114, 0xF>(v);   // row_shr:4
    v = dpp_add<0x118, 0xF>(v);   // row_shr:8
    v = dpp_add<0x142, 0xA>(v);   // row_bcast:15
    v = dpp_add<0x143, 0xC>(v);   // row_bcast:31 -> lane63 = wave total
    return v;
}
__device__ __forceinline__ float lane63(float v) {
    return __uint_as_float(__builtin_amdgcn_readlane(__float_as_uint(v), 63));
}

// Layout: c (64) + w (64) floats in regs/AGPR-parked + temps; cap 256 via
// launch_bounds(64,2) -> no spill (R17 lesson). No per-element state across
// iterations; emit recomputes x, 1/AB2 once at (lam, dlam).
__global__ __launch_bounds__(BLOCK, 2) void ipm_knapsack_kernel(
        const float* __restrict__ costs,
        const float* __restrict__ weights,
        float* __restrict__ out) {
    const int row = blockIdx.x;
    const int t   = threadIdx.x;

    v2f w[NG], c[NG];

    // ---- Load w and this row's c (negated); accumulate sum(w) ----
    const float4* wg = reinterpret_cast<const float4*>(weights);
    const float4* cg = reinterpret_cast<const float4*>(costs + (size_t)row * N_ELEM);
    float wsp = 0.0f;
    #pragma unroll
    for (int j = 0; j < NG / 2; ++j) {
        F4V2 ww, cc;
        ww.f4 = wg[t + BLOCK * j];
        cc.f4 = cg[t + BLOCK * j];
        cc.f4.x = -cc.f4.x; cc.f4.y = -cc.f4.y; cc.f4.z = -cc.f4.z; cc.f4.w = -cc.f4.w;
        wsp += (ww.f4.x + ww.f4.y) + (ww.f4.z + ww.f4.w);
        w[2 * j] = ww.v[0]; w[2 * j + 1] = ww.v[1];
        c[2 * j] = cc.v[0]; c[2 * j + 1] = cc.v[1];
    }
    // capadj = 0.5*sum(w) - CAPACITY (loop-invariant scalar).
    const float ws_tot = lane63(wave_sum63(wsp));
    const float capadj = fmaf(0.5f, ws_tot, -CAPACITY);

    float lam = 0.0f, dl = 0.0f;

    for (int it = 0; it < NITER; ++it) {
        // mu: 1,1,1, .25, .0625, .015625, .00390625, then DAMPING forever.
        const float mu = (it < N_MU1) ? 1.0f
                       : (it < FIRST_FINAL)
                         ? __uint_as_float((unsigned)(127 - 2 * (it - (N_MU1 - 1))) << 23)
                         : DAMPING;
        const float two_mu = 2.0f * mu;
        const float mu4sq  = 4.0f * mu * mu;

        v2f s0 = {0.0f, 0.0f}, s2 = {0.0f, 0.0f};
        #pragma unroll
        for (int k = 0; k < NG; ++k) {
            const v2f wk   = w[k];
            const v2f r_   = lam * wk + c[k];
            const v2f a_   = __builtin_elementwise_abs(r_);
            const v2f D_   = r_ * r_ + mu4sq;
            const v2f s_   = pk_sqrt(D_);
            const v2f den_ = (a_ + two_mu) + s_;
            const v2f AB2_ = two_mu * s_ + D_;
            const v2f rq_  = pk_rcp(den_ * AB2_);
            const v2f xp_  = two_mu * (rq_ * AB2_);    // x' in (0,0.5]
            const v2f cw_  = pk_copysign(wk, r_);      // sign-folded weight
            s0 = cw_ * (xp_ - 0.5f) + s0;              // sum w*x - 0.5*sum w
            s2 = (wk * wk) * (rq_ * den_) + s2;        // sum w^2/AB2
        }

        // ---- Wave-only reduce: 6 DPP adds per value, then readlane 63 ----
        const float s0t = lane63(wave_sum63(s0.x + s0.y));
        const float s2t = lane63(wave_sum63(s2.x + s2.y));
        // Schur: dl = (sum(w*x) - cap) / (mu * sum(w^2/AB2)), divergence-
        // clamped (inert on proven path; caps flat-region Newton cascade).
        dl = (s0t + capadj) * raw_rcp(mu * s2t);
        dl = fminf(fmaxf(dl, -DL_CLAMP), DL_CLAMP);

        // Break WITHOUT applying dlam: (lam, dlam) feeds the emit refine.
        // Gate fires ~it 9-11 (R16-proven). Uniform branch (readlane SGPR).
        if ((it >= GATE_IT && fabsf(dl) < GATE_EPS) || it == NITER - 1) break;
        lam += dl;
    }

    // ---- Emit pass (R18-identical): recompute x, 1/AB2 at (lam, DAMPING);
    // out = x - dlam * (mu*w)/AB2  (== reference _kkt_refine with F1 == 0).
    {
        const float mu = DAMPING;
        const float two_mu = 2.0f * mu;
        const float mu4sq  = 4.0f * mu * mu;
        float4* og = reinterpret_cast<float4*>(out + (size_t)row * N_ELEM);
        #pragma unroll
        for (int j = 0; j < NG / 2; ++j) {
            F4V2 ov;
            #pragma unroll
            for (int h = 0; h < 2; ++h) {
                const int k = 2 * j + h;
                const v2f wk   = w[k];
                const v2f r_   = lam * wk + c[k];
                const v2f a_   = __builtin_elementwise_abs(r_);
                const v2f D_   = r_ * r_ + mu4sq;
                const v2f s_   = pk_sqrt(D_);
                const v2f den_ = (a_ + two_mu) + s_;
                const v2f AB2_ = two_mu * s_ + D_;
                const v2f rq_  = pk_rcp(den_ * AB2_);
                const v2f xp_  = two_mu * (rq_ * AB2_);
                const v2f xk_  = 0.5f - pk_copysign(0.5f - xp_, r_);
                const v2f wi_  = (mu * wk) * (rq_ * den_);
                ov.v[h] = xk_ - dl * wi_;
            }
            og[t + BLOCK * j] = ov.f4;
        }
    }
}

extern "C" void kernel_launch(void* const* d_in, const int* in_sizes, int n_in,
                              void* d_out, int out_size, void* d_ws, size_t ws_size,
                              hipStream_t stream) {
    const float* costs   = (const float*)d_in[0];
    const float* weights = (const float*)d_in[1];
    float* out = (float*)d_out;
    const int B = in_sizes[0] / N_ELEM;   // 2048 rows -> 2048 single-wave blocks
    ipm_knapsack_kernel<<<B, BLOCK, 0, stream>>>(costs, weights, out);
}